// Round 18
// baseline (182.341 us; speedup 1.0000x reference)
//
#include <hip/hip_runtime.h>
#include <cstdint>
#include <cstddef>

#define DEV static __device__ __forceinline__

typedef __attribute__((ext_vector_type(8))) short short8;   // 8 bf16 MFMA A/B frag
typedef __attribute__((ext_vector_type(16))) float f32x16;  // 32x32 C/D frag
typedef __attribute__((ext_vector_type(4))) unsigned short u16x4;
typedef __attribute__((ext_vector_type(2))) unsigned short u16x2;

constexpr int kB = 4, kN = 2048, kD = 384, kH = 6, kDFF = 2048;
constexpr int kM = kB * kN;          // 8192 token rows
constexpr int kBH = kB * kH;         // 24 (b,h) pairs
// Q pre-scale folded into QKV epilogue: 1/sqrt(64) * log2(e)  -> softmax in exp2 domain
constexpr float kQPre = 0.18033688011112042f;

DEV float exp2fast(float f) { return __builtin_amdgcn_exp2f(f); }  // v_exp_f32 (base-2)

DEV unsigned short f2b(float f) {    // fp32 -> bf16 bits, round-nearest-even
  union { float fp; uint32_t u; } v; v.fp = f;
  return (unsigned short)((v.u + 0x7fffu + ((v.u >> 16) & 1u)) >> 16);
}

DEV void gload16(const unsigned short* g, unsigned short* l) {
  __builtin_amdgcn_global_load_lds(
      (const __attribute__((address_space(1))) unsigned int*)g,
      (__attribute__((address_space(3))) unsigned int*)l, 16, 0, 0);
}

// tanh-form GELU in exp2 domain (max abs err ~3e-4, < bf16 rounding)
DEV float gelu_fast(float x) {
  float t = exp2fast(x * (2.3022081f + 0.1029432f * x * x));
  return x - x * __builtin_amdgcn_rcpf(t + 1.0f);
}

// ---- fused prologue: 3 weight cast+transposes + LayerNorm1 ------------------
__global__ __launch_bounds__(256) void k_pre(
    const float* __restrict__ wqkv, unsigned short* __restrict__ wqkvT,
    const float* __restrict__ w1,   unsigned short* __restrict__ w1T,
    const float* __restrict__ w2,   unsigned short* __restrict__ w2T,
    const float* __restrict__ x, const float* __restrict__ g,
    const float* __restrict__ bta, unsigned short* __restrict__ y) {
  const int tid = threadIdx.x;
  if (blockIdx.x >= 492) {                    // ---- LayerNorm rows ----
    int row  = (blockIdx.x - 492) * 4 + (tid >> 6);
    int lane = tid & 63;
    const float* xr = x + (size_t)row * kD;
    float4 a = *(const float4*)(xr + lane * 4);
    float2 c = *(const float2*)(xr + 256 + lane * 2);
    float s  = a.x + a.y + a.z + a.w + c.x + c.y;
    float ss = a.x*a.x + a.y*a.y + a.z*a.z + a.w*a.w + c.x*c.x + c.y*c.y;
#pragma unroll
    for (int m = 1; m < 64; m <<= 1) {
      s  += __shfl_xor(s,  m, 64);
      ss += __shfl_xor(ss, m, 64);
    }
    float mean = s * (1.0f / kD);
    float var  = ss * (1.0f / kD) - mean * mean;
    float r = rsqrtf(var + 1e-5f);
    float4 g4 = *(const float4*)(g + lane * 4);
    float2 g2 = *(const float2*)(g + 256 + lane * 2);
    float4 b4 = *(const float4*)(bta + lane * 4);
    float2 b2 = *(const float2*)(bta + 256 + lane * 2);
    unsigned short* yr = y + (size_t)row * kD;
    u16x4 o4;
    o4[0] = f2b((a.x - mean) * r * g4.x + b4.x);
    o4[1] = f2b((a.y - mean) * r * g4.y + b4.y);
    o4[2] = f2b((a.z - mean) * r * g4.z + b4.z);
    o4[3] = f2b((a.w - mean) * r * g4.w + b4.w);
    *(u16x4*)(yr + lane * 4) = o4;
    u16x2 o2;
    o2[0] = f2b((c.x - mean) * r * g2.x + b2.x);
    o2[1] = f2b((c.y - mean) * r * g2.y + b2.y);
    *(u16x2*)(yr + 256 + lane * 2) = o2;
    return;
  }
  // ---- weight transpose tiles ----
  __shared__ unsigned short t[64][66];
  int idx = blockIdx.x;
  const float* w; unsigned short* wT; int K, Nn, nbk;
  if (idx < 108)      { w = wqkv; wT = wqkvT; K = 384;  Nn = 1152; nbk = 6; }
  else if (idx < 300) { w = w1;   wT = w1T;   K = 384;  Nn = 2048; nbk = 6;  idx -= 108; }
  else                { w = w2;   wT = w2T;   K = 2048; Nn = 384;  nbk = 32; idx -= 300; }
  const int bk = idx % nbk, bn = idx / nbk;
  const int k0 = bk << 6, n0 = bn << 6;
  const int cl = tid & 63, rw = tid >> 6;
#pragma unroll
  for (int it = 0; it < 16; ++it) {
    int kk = it * 4 + rw;
    t[cl][kk] = f2b(w[(size_t)(k0 + kk) * Nn + n0 + cl]);
  }
  __syncthreads();
  const int kq = (tid & 15) << 2;
  const int nr = tid >> 4;
#pragma unroll
  for (int it = 0; it < 4; ++it) {
    int nn = it * 16 + nr;
    u16x4 v;
    v[0] = t[nn][kq]; v[1] = t[nn][kq + 1]; v[2] = t[nn][kq + 2]; v[3] = t[nn][kq + 3];
    *(u16x4*)&wT[(size_t)(n0 + nn) * K + k0 + kq] = v;
  }
}

// ---- LayerNorm (standalone, for LN2) ---------------------------------------
__global__ __launch_bounds__(256) void k_layernorm(
    const float* __restrict__ x, const float* __restrict__ g,
    const float* __restrict__ bta, unsigned short* __restrict__ y) {
  int row  = blockIdx.x * 4 + (threadIdx.x >> 6);
  int lane = threadIdx.x & 63;
  const float* xr = x + (size_t)row * kD;
  float4 a = *(const float4*)(xr + lane * 4);
  float2 c = *(const float2*)(xr + 256 + lane * 2);
  float s  = a.x + a.y + a.z + a.w + c.x + c.y;
  float ss = a.x*a.x + a.y*a.y + a.z*a.z + a.w*a.w + c.x*c.x + c.y*c.y;
#pragma unroll
  for (int m = 1; m < 64; m <<= 1) {
    s  += __shfl_xor(s,  m, 64);
    ss += __shfl_xor(ss, m, 64);
  }
  float mean = s * (1.0f / kD);
  float var  = ss * (1.0f / kD) - mean * mean;
  float r = rsqrtf(var + 1e-5f);
  float4 g4 = *(const float4*)(g + lane * 4);
  float2 g2 = *(const float2*)(g + 256 + lane * 2);
  float4 b4 = *(const float4*)(bta + lane * 4);
  float2 b2 = *(const float2*)(bta + 256 + lane * 2);
  unsigned short* yr = y + (size_t)row * kD;
  u16x4 o4;
  o4[0] = f2b((a.x - mean) * r * g4.x + b4.x);
  o4[1] = f2b((a.y - mean) * r * g4.y + b4.y);
  o4[2] = f2b((a.z - mean) * r * g4.z + b4.z);
  o4[3] = f2b((a.w - mean) * r * g4.w + b4.w);
  *(u16x4*)(yr + lane * 4) = o4;
  u16x2 o2;
  o2[0] = f2b((c.x - mean) * r * g2.x + b2.x);
  o2[1] = f2b((c.y - mean) * r * g2.y + b2.y);
  *(u16x2*)(yr + 256 + lane * 2) = o2;
}

// ---- bf16 MFMA GEMM (32x32x16 core, BK=64): C = A @ Bt^T + bias -------------
// (R17-verified.)  TM x 128 tile, BK=64, 4 waves, dbuf LDS, slot-XOR swizzle.
// MODE 0: QKV epilogue   MODE 1: tanh-GELU -> bf16   MODE 2: +residual -> fp32
template <int MODE, int TM>
__global__ __launch_bounds__(256) void k_gemm(
    const unsigned short* __restrict__ A, const unsigned short* __restrict__ Bt,
    const float* __restrict__ bias, int K, int Nn, int nbm,
    unsigned short* __restrict__ oq, unsigned short* __restrict__ okk,
    unsigned short* __restrict__ ov, unsigned short* __restrict__ oh,
    const float* __restrict__ res, float* __restrict__ out) {
  constexpr int FI = 1;                          // 32-frags in m per wave
  constexpr int FJ = (TM >= 64) ? 2 : 1;         // 32-frags in n per wave
  __shared__ unsigned short lA[2][TM * 64];
  __shared__ unsigned short lB[2][128 * 64];
  const int tid = threadIdx.x, wid = tid >> 6, lane = tid & 63;
  const int bm = blockIdx.x % nbm, bn = blockIdx.x / nbm;
  const int m0 = bm * TM, n0 = bn * 128;
  const int wr = (TM >= 64) ? (wid >> 1) : 0;
  const int wc = (TM >= 64) ? (wid & 1) : wid;
  const int wmo = wr * 32;
  const int wno = wc * (FJ * 32);
  const int l31 = lane & 31, lh = lane >> 5;
  const int rsw = l31 & 7;                  // read-side slot XOR key

  f32x16 acc[FI][FJ];
#pragma unroll
  for (int i = 0; i < FI; i++)
#pragma unroll
    for (int j = 0; j < FJ; j++)
#pragma unroll
      for (int r = 0; r < 16; r++) acc[i][j][r] = 0.f;

  const int srow = tid >> 3;                // 32 rows per pass, 8 threads/row
  const int sslot = tid & 7;

  auto stage = [&](int buf, int k0) {
#pragma unroll
    for (int p = 0; p < 4; p++) {           // B: 128 rows
      int row = (p << 5) + srow;
      int sl  = (sslot ^ (row & 7)) << 3;
      gload16(Bt + (size_t)(n0 + row) * K + k0 + sl,
              &lB[buf][(row << 6) + (sslot << 3)]);
    }
#pragma unroll
    for (int p = 0; p < TM / 32; p++) {     // A: TM rows
      int row = (p << 5) + srow;
      int sl  = (sslot ^ (row & 7)) << 3;
      gload16(A + (size_t)(m0 + row) * K + k0 + sl,
              &lA[buf][(row << 6) + (sslot << 3)]);
    }
  };

  stage(0, 0);

  const int nkt = K >> 6;
  for (int kt = 0; kt < nkt; ++kt) {
    const int cur = kt & 1;
    __syncthreads();                        // drains stage(cur); protects buf[cur^1]
    if (kt + 1 < nkt) stage(cur ^ 1, (kt + 1) << 6);
    short8 af[FI][4], bf[FJ][4];
#pragma unroll
    for (int i = 0; i < FI; i++)
#pragma unroll
      for (int ks = 0; ks < 4; ks++)
        af[i][ks] = *(const short8*)&lA[cur][((wmo + (i << 5) + l31) << 6) +
                                            ((((ks << 1) + lh) ^ rsw) << 3)];
#pragma unroll
    for (int j = 0; j < FJ; j++)
#pragma unroll
      for (int ks = 0; ks < 4; ks++)
        bf[j][ks] = *(const short8*)&lB[cur][((wno + (j << 5) + l31) << 6) +
                                            ((((ks << 1) + lh) ^ rsw) << 3)];
#pragma unroll
    for (int i = 0; i < FI; i++)
#pragma unroll
      for (int j = 0; j < FJ; j++)
#pragma unroll
        for (int ks = 0; ks < 4; ks++)
          acc[i][j] = __builtin_amdgcn_mfma_f32_32x32x16_bf16(af[i][ks], bf[j][ks],
                                                              acc[i][j], 0, 0, 0);
  }

  // epilogue: col = lane&31 (fixed per fj), row = (reg&3)+8*(reg>>2)+4*lh
#pragma unroll
  for (int i = 0; i < FI; i++) {
#pragma unroll
    for (int j = 0; j < FJ; j++) {
      int col = n0 + wno + (j << 5) + l31;
      float bv = bias[col];
#pragma unroll
      for (int reg = 0; reg < 16; ++reg) {
        int m = m0 + wmo + (i << 5) + (reg & 3) + ((reg >> 2) << 3) + (lh << 2);
        float cvl = acc[i][j][reg] + bv;
        if (MODE == 0) {
          int bI = m >> 11, nI = m & 2047;
          if (col < 384) {
            int hh = col >> 6, dd = col & 63;
            oq[(((size_t)bI * kH + hh) * kN + nI) * 64 + dd] = f2b(cvl * kQPre);
          } else if (col < 768) {
            int c2 = col - 384; int hh = c2 >> 6, dd = c2 & 63;
            okk[(((size_t)bI * kH + hh) * kN + nI) * 64 + dd] = f2b(cvl);
          } else {
            int c2 = col - 768; int hh = c2 >> 6, dd = c2 & 63;
            ov[(((size_t)bI * kH + hh) * 64 + dd) * kN + nI] = f2b(cvl);
          }
        } else if (MODE == 1) {
          oh[(size_t)m * kDFF + col] = f2b(gelu_fast(cvl));
        } else {
          size_t idx = (size_t)m * kD + col;
          out[idx] = res[idx] + cvl;
        }
      }
    }
  }
}

// ---- flash attention, 32x32 frags, BARRIER-FREE loop ------------------------
// K/V per (b,h) = 512KB and XCD-swizzled blocks keep 3 bh per XCD L2 (1.5MB,
// resident) -> LDS staging of L2-resident data is pure overhead (CM #7).
// K A-frags and V^T A-frags are read DIRECTLY from global (16B aligned, same
// fragment math as R16-verified LDS version). No barriers, no staging, no
// swizzle in the loop; waves fully independent. P^T stays in registers.
// LDS only for the final kv-half merge (16.9KB, own barriers).
__global__ __launch_bounds__(256) void k_attn(
    const unsigned short* __restrict__ Q, const unsigned short* __restrict__ Kg,
    const unsigned short* __restrict__ Vt, const float* __restrict__ x,
    float* __restrict__ x2) {
  __shared__ float fb[64 * 65 + 64];          // merge buffer + l totals
  const int tid = threadIdx.x, wid = tid >> 6, lane = tid & 63;
  const int swz = (blockIdx.x & 7) * (gridDim.x >> 3) + (blockIdx.x >> 3);
  const int bh = swz >> 5, qt = swz & 31;
  const int b = bh / kH, h = bh - b * kH;
  const unsigned short* Qp = Q  + (size_t)bh * kN * 64;
  const unsigned short* Kp = Kg + (size_t)bh * kN * 64;
  const unsigned short* Vp = Vt + (size_t)bh * 64 * kN;
  const int l31 = lane & 31, lh = lane >> 5;
  const int qh = wid & 1, kvh = wid >> 1;
  const int q0 = qt * 64;

  // Q B-frags: col q = q0+qh*32+l31, k(d) = ks*16+lh*8
  short8 qb[4];
#pragma unroll
  for (int ks = 0; ks < 4; ++ks)
    qb[ks] = *(const short8*)(Qp + (size_t)(q0 + qh * 32 + l31) * 64 + ks * 16 + lh * 8);

  f32x16 o[2];
#pragma unroll
  for (int dt = 0; dt < 2; ++dt)
#pragma unroll
    for (int r = 0; r < 16; r++) o[dt][r] = 0.f;
  float l_r = 0.f;

  // per-wave K row pointer (row kv = t*64 + kvh*32 + l31), V row base
  const unsigned short* Kr = Kp + (size_t)(kvh * 32 + l31) * 64;
  const unsigned short* Vr0 = Vp + (size_t)l31 * kN + kvh * 32;        // dt=0
  const unsigned short* Vr1 = Vp + (size_t)(32 + l31) * kN + kvh * 32; // dt=1

  constexpr int kNT = kN / 64;                // 32 tiles, full KV
  for (int t = 0; t < kNT; ++t) {
    // S^T[kv32 of kvh][q32 of qh] = mfma(K_A, Q_B) over d=64 (4 k-steps)
    const unsigned short* kt = Kr + (size_t)t * 64 * 64;
    f32x16 s;
#pragma unroll
    for (int r = 0; r < 16; r++) s[r] = 0.f;
#pragma unroll
    for (int ks = 0; ks < 4; ++ks) {
      short8 kf = *(const short8*)(kt + ks * 16 + lh * 8);
      s = __builtin_amdgcn_mfma_f32_32x32x16_bf16(kf, qb[ks], s, 0, 0, 0);
    }

    // P = exp2(s); pack groups g: Aw[g]=pk(p[4g],p[4g+1]), Bw[g]=pk(p[4g+2],p[4g+3])
    uint32_t Aw[4], Bw[4];
    float lsum = 0.f;
#pragma unroll
    for (int g = 0; g < 4; ++g) {
      float p0 = exp2fast(s[4 * g + 0]);
      float p1 = exp2fast(s[4 * g + 1]);
      float p2 = exp2fast(s[4 * g + 2]);
      float p3 = exp2fast(s[4 * g + 3]);
      lsum += (p0 + p1) + (p2 + p3);
      asm("v_cvt_pk_bf16_f32 %0, %1, %2" : "=v"(Aw[g]) : "v"(p0), "v"(p1));
      asm("v_cvt_pk_bf16_f32 %0, %1, %2" : "=v"(Bw[g]) : "v"(p2), "v"(p3));
    }
    l_r += lsum + __shfl_xor(lsum, 32, 64);   // wave's kv-half row-sum for q=l31

    // Build P^T B-frags in-register (reg group = lh_dest+2ks, src half = jj>>2)
    short8 pb[2];
#pragma unroll
    for (int ks = 0; ks < 2; ++ks) {
      uint32_t cA = lh ? Aw[2 * ks + 1] : Aw[2 * ks];
      uint32_t cB = lh ? Bw[2 * ks + 1] : Bw[2 * ks];
      uint32_t dA = lh ? Aw[2 * ks] : Aw[2 * ks + 1];
      uint32_t dB = lh ? Bw[2 * ks] : Bw[2 * ks + 1];
      uint32_t sA = __shfl_xor(dA, 32, 64);
      uint32_t sB = __shfl_xor(dB, 32, 64);
      union { uint32_t u[4]; short8 s8; } bld;
      bld.u[0] = lh ? sA : cA;
      bld.u[1] = lh ? sB : cB;
      bld.u[2] = lh ? cA : sA;
      bld.u[3] = lh ? cB : sB;
      pb[ks] = bld.s8;
    }

    // O^T[d 2x32][q32] += V^T P^T ; V^T A-frag row d = dt*32+l31, k = kv local
#pragma unroll
    for (int ks = 0; ks < 2; ++ks) {
      short8 va0 = *(const short8*)(Vr0 + t * 64 + ks * 16 + lh * 8);
      short8 va1 = *(const short8*)(Vr1 + t * 64 + ks * 16 + lh * 8);
      o[0] = __builtin_amdgcn_mfma_f32_32x32x16_bf16(va0, pb[ks], o[0], 0, 0, 0);
      o[1] = __builtin_amdgcn_mfma_f32_32x32x16_bf16(va1, pb[ks], o[1], 0, 0, 0);
    }
  }

  // ---- merge kv-halves + coalesced write: fb[q64][d64] f32 (stride 65) ----
  float* lb = fb + 64 * 65;                   // l totals [64]
  const int q = qh * 32 + l31;
  if (kvh == 1) {
#pragma unroll
    for (int dt = 0; dt < 2; ++dt)
#pragma unroll
      for (int reg = 0; reg < 16; ++reg) {
        int d = (dt << 5) + (reg & 3) + ((reg >> 2) << 3) + (lh << 2);
        fb[q * 65 + d] = o[dt][reg];
      }
    if (lh == 0) lb[q] = l_r;
  }
  __syncthreads();
  if (kvh == 0) {
#pragma unroll
    for (int dt = 0; dt < 2; ++dt)
#pragma unroll
      for (int reg = 0; reg < 16; ++reg) {
        int d = (dt << 5) + (reg & 3) + ((reg >> 2) << 3) + (lh << 2);
        fb[q * 65 + d] += o[dt][reg];
      }
    if (lh == 0) lb[q] += l_r;
  }
  __syncthreads();
  // write-out: thread -> (row=tid>>2, 16-d chunk), fully coalesced x/x2
  {
    int row = tid >> 2, dc = (tid & 3) << 4;
    float inv = __builtin_amdgcn_rcpf(lb[row]);
    size_t base = ((size_t)(b * kN + q0 + row)) * kD + h * 64 + dc;
#pragma unroll
    for (int i = 0; i < 16; i += 4) {
      float4 xv = *(const float4*)(x + base + i);
      float4 ov;
      ov.x = xv.x + fb[row * 65 + dc + i + 0] * inv;
      ov.y = xv.y + fb[row * 65 + dc + i + 1] * inv;
      ov.z = xv.z + fb[row * 65 + dc + i + 2] * inv;
      ov.w = xv.w + fb[row * 65 + dc + i + 3] * inv;
      *(float4*)(x2 + base + i) = ov;
    }
  }
}

extern "C" void kernel_launch(void* const* d_in, const int* in_sizes, int n_in,
                              void* d_out, int out_size, void* d_ws, size_t ws_size,
                              hipStream_t stream) {
  const float* x    = (const float*)d_in[0];
  const float* ng   = (const float*)d_in[1];
  const float* nb   = (const float*)d_in[2];
  const float* wqkv = (const float*)d_in[3];
  const float* bqkv = (const float*)d_in[4];
  const float* w1   = (const float*)d_in[5];
  const float* b1   = (const float*)d_in[6];
  const float* w2   = (const float*)d_in[7];
  const float* b2   = (const float*)d_in[8];
  float* out = (float*)d_out;

  char* p = (char*)d_ws;
  auto take = [&](size_t bytes) -> char* {
    char* r = p; p += (bytes + 255) & ~(size_t)255; return r;
  };
  unsigned short* y     = (unsigned short*)take((size_t)kM * kD * 2);
  unsigned short* wqkvT = (unsigned short*)take((size_t)3 * kD * kD * 2);
  unsigned short* w1T   = (unsigned short*)take((size_t)kDFF * kD * 2);
  unsigned short* w2T   = (unsigned short*)take((size_t)kD * kDFF * 2);
  unsigned short* Qw    = (unsigned short*)take((size_t)kM * kD * 2);
  unsigned short* Kw    = (unsigned short*)take((size_t)kM * kD * 2);
  unsigned short* Vtw   = (unsigned short*)take((size_t)kM * kD * 2);
  float*          x2    = (float*)take((size_t)kM * kD * 4);
  unsigned short* hbuf  = (unsigned short*)take((size_t)kM * kDFF * 2);

  k_pre<<<492 + kM / 4, 256, 0, stream>>>(wqkv, wqkvT, w1, w1T, w2, w2T,
                                          x, ng, nb, y);
  k_gemm<0, 64><<<128 * 9, 256, 0, stream>>>(y, wqkvT, bqkv, kD, 3 * kD, 128,
                                             Qw, Kw, Vtw, nullptr, nullptr, nullptr);
  k_attn<<<kBH * 32, 256, 0, stream>>>(Qw, Kw, Vtw, x, x2);
  k_layernorm<<<kM / 4, 256, 0, stream>>>(x2, ng, nb, y);
  k_gemm<1, 64><<<128 * 16, 256, 0, stream>>>(y, w1T, b1, kD, kDFF, 128,
                                              nullptr, nullptr, nullptr, hbuf, nullptr, nullptr);
  k_gemm<2, 32><<<256 * 3, 256, 0, stream>>>(hbuf, w2T, b2, kDFF, kD, 256,
                                             nullptr, nullptr, nullptr, nullptr, x2, out);
}

// Round 19
// 134.919 us; speedup vs baseline: 1.3515x; 1.3515x over previous
//
#include <hip/hip_runtime.h>
#include <cstdint>
#include <cstddef>

#define DEV static __device__ __forceinline__

typedef __attribute__((ext_vector_type(8))) short short8;   // 8 bf16 MFMA A/B frag
typedef __attribute__((ext_vector_type(16))) float f32x16;  // 32x32 C/D frag
typedef __attribute__((ext_vector_type(4))) unsigned short u16x4;
typedef __attribute__((ext_vector_type(2))) unsigned short u16x2;

constexpr int kB = 4, kN = 2048, kD = 384, kH = 6, kDFF = 2048;
constexpr int kM = kB * kN;          // 8192 token rows
constexpr int kBH = kB * kH;         // 24 (b,h) pairs
// Q pre-scale folded into QKV epilogue: 1/sqrt(64) * log2(e)  -> softmax in exp2 domain
constexpr float kQPre = 0.18033688011112042f;

DEV float exp2fast(float f) { return __builtin_amdgcn_exp2f(f); }  // v_exp_f32 (base-2)

DEV unsigned short f2b(float f) {    // fp32 -> bf16 bits, round-nearest-even
  union { float fp; uint32_t u; } v; v.fp = f;
  return (unsigned short)((v.u + 0x7fffu + ((v.u >> 16) & 1u)) >> 16);
}

DEV void gload16(const unsigned short* g, unsigned short* l) {
  __builtin_amdgcn_global_load_lds(
      (const __attribute__((address_space(1))) unsigned int*)g,
      (__attribute__((address_space(3))) unsigned int*)l, 16, 0, 0);
}

// tanh-form GELU in exp2 domain (max abs err ~3e-4, < bf16 rounding)
DEV float gelu_fast(float x) {
  float t = exp2fast(x * (2.3022081f + 0.1029432f * x * x));
  return x - x * __builtin_amdgcn_rcpf(t + 1.0f);
}

// ---- fused prologue: 3 weight cast+transposes + LayerNorm1 ------------------
__global__ __launch_bounds__(256) void k_pre(
    const float* __restrict__ wqkv, unsigned short* __restrict__ wqkvT,
    const float* __restrict__ w1,   unsigned short* __restrict__ w1T,
    const float* __restrict__ w2,   unsigned short* __restrict__ w2T,
    const float* __restrict__ x, const float* __restrict__ g,
    const float* __restrict__ bta, unsigned short* __restrict__ y) {
  const int tid = threadIdx.x;
  if (blockIdx.x >= 492) {                    // ---- LayerNorm rows ----
    int row  = (blockIdx.x - 492) * 4 + (tid >> 6);
    int lane = tid & 63;
    const float* xr = x + (size_t)row * kD;
    float4 a = *(const float4*)(xr + lane * 4);
    float2 c = *(const float2*)(xr + 256 + lane * 2);
    float s  = a.x + a.y + a.z + a.w + c.x + c.y;
    float ss = a.x*a.x + a.y*a.y + a.z*a.z + a.w*a.w + c.x*c.x + c.y*c.y;
#pragma unroll
    for (int m = 1; m < 64; m <<= 1) {
      s  += __shfl_xor(s,  m, 64);
      ss += __shfl_xor(ss, m, 64);
    }
    float mean = s * (1.0f / kD);
    float var  = ss * (1.0f / kD) - mean * mean;
    float r = rsqrtf(var + 1e-5f);
    float4 g4 = *(const float4*)(g + lane * 4);
    float2 g2 = *(const float2*)(g + 256 + lane * 2);
    float4 b4 = *(const float4*)(bta + lane * 4);
    float2 b2 = *(const float2*)(bta + 256 + lane * 2);
    unsigned short* yr = y + (size_t)row * kD;
    u16x4 o4;
    o4[0] = f2b((a.x - mean) * r * g4.x + b4.x);
    o4[1] = f2b((a.y - mean) * r * g4.y + b4.y);
    o4[2] = f2b((a.z - mean) * r * g4.z + b4.z);
    o4[3] = f2b((a.w - mean) * r * g4.w + b4.w);
    *(u16x4*)(yr + lane * 4) = o4;
    u16x2 o2;
    o2[0] = f2b((c.x - mean) * r * g2.x + b2.x);
    o2[1] = f2b((c.y - mean) * r * g2.y + b2.y);
    *(u16x2*)(yr + 256 + lane * 2) = o2;
    return;
  }
  // ---- weight transpose tiles ----
  __shared__ unsigned short t[64][66];
  int idx = blockIdx.x;
  const float* w; unsigned short* wT; int K, Nn, nbk;
  if (idx < 108)      { w = wqkv; wT = wqkvT; K = 384;  Nn = 1152; nbk = 6; }
  else if (idx < 300) { w = w1;   wT = w1T;   K = 384;  Nn = 2048; nbk = 6;  idx -= 108; }
  else                { w = w2;   wT = w2T;   K = 2048; Nn = 384;  nbk = 32; idx -= 300; }
  const int bk = idx % nbk, bn = idx / nbk;
  const int k0 = bk << 6, n0 = bn << 6;
  const int cl = tid & 63, rw = tid >> 6;
#pragma unroll
  for (int it = 0; it < 16; ++it) {
    int kk = it * 4 + rw;
    t[cl][kk] = f2b(w[(size_t)(k0 + kk) * Nn + n0 + cl]);
  }
  __syncthreads();
  const int kq = (tid & 15) << 2;
  const int nr = tid >> 4;
#pragma unroll
  for (int it = 0; it < 4; ++it) {
    int nn = it * 16 + nr;
    u16x4 v;
    v[0] = t[nn][kq]; v[1] = t[nn][kq + 1]; v[2] = t[nn][kq + 2]; v[3] = t[nn][kq + 3];
    *(u16x4*)&wT[(size_t)(n0 + nn) * K + k0 + kq] = v;
  }
}

// ---- LayerNorm (standalone, for LN2) ---------------------------------------
__global__ __launch_bounds__(256) void k_layernorm(
    const float* __restrict__ x, const float* __restrict__ g,
    const float* __restrict__ bta, unsigned short* __restrict__ y) {
  int row  = blockIdx.x * 4 + (threadIdx.x >> 6);
  int lane = threadIdx.x & 63;
  const float* xr = x + (size_t)row * kD;
  float4 a = *(const float4*)(xr + lane * 4);
  float2 c = *(const float2*)(xr + 256 + lane * 2);
  float s  = a.x + a.y + a.z + a.w + c.x + c.y;
  float ss = a.x*a.x + a.y*a.y + a.z*a.z + a.w*a.w + c.x*c.x + c.y*c.y;
#pragma unroll
  for (int m = 1; m < 64; m <<= 1) {
    s  += __shfl_xor(s,  m, 64);
    ss += __shfl_xor(ss, m, 64);
  }
  float mean = s * (1.0f / kD);
  float var  = ss * (1.0f / kD) - mean * mean;
  float r = rsqrtf(var + 1e-5f);
  float4 g4 = *(const float4*)(g + lane * 4);
  float2 g2 = *(const float2*)(g + 256 + lane * 2);
  float4 b4 = *(const float4*)(bta + lane * 4);
  float2 b2 = *(const float2*)(bta + 256 + lane * 2);
  unsigned short* yr = y + (size_t)row * kD;
  u16x4 o4;
  o4[0] = f2b((a.x - mean) * r * g4.x + b4.x);
  o4[1] = f2b((a.y - mean) * r * g4.y + b4.y);
  o4[2] = f2b((a.z - mean) * r * g4.z + b4.z);
  o4[3] = f2b((a.w - mean) * r * g4.w + b4.w);
  *(u16x4*)(yr + lane * 4) = o4;
  u16x2 o2;
  o2[0] = f2b((c.x - mean) * r * g2.x + b2.x);
  o2[1] = f2b((c.y - mean) * r * g2.y + b2.y);
  *(u16x2*)(yr + 256 + lane * 2) = o2;
}

// ---- bf16 MFMA GEMM (32x32x16 core, BK=64): C = A @ Bt^T + bias -------------
// (R17-verified.)  TM x 128 tile, BK=64, 4 waves, dbuf LDS, slot-XOR swizzle.
// MODE 0: QKV epilogue   MODE 1: tanh-GELU -> bf16   MODE 2: +residual -> fp32
template <int MODE, int TM>
__global__ __launch_bounds__(256) void k_gemm(
    const unsigned short* __restrict__ A, const unsigned short* __restrict__ Bt,
    const float* __restrict__ bias, int K, int Nn, int nbm,
    unsigned short* __restrict__ oq, unsigned short* __restrict__ okk,
    unsigned short* __restrict__ ov, unsigned short* __restrict__ oh,
    const float* __restrict__ res, float* __restrict__ out) {
  constexpr int FI = 1;                          // 32-frags in m per wave
  constexpr int FJ = (TM >= 64) ? 2 : 1;         // 32-frags in n per wave
  __shared__ unsigned short lA[2][TM * 64];
  __shared__ unsigned short lB[2][128 * 64];
  const int tid = threadIdx.x, wid = tid >> 6, lane = tid & 63;
  const int bm = blockIdx.x % nbm, bn = blockIdx.x / nbm;
  const int m0 = bm * TM, n0 = bn * 128;
  const int wr = (TM >= 64) ? (wid >> 1) : 0;
  const int wc = (TM >= 64) ? (wid & 1) : wid;
  const int wmo = wr * 32;
  const int wno = wc * (FJ * 32);
  const int l31 = lane & 31, lh = lane >> 5;
  const int rsw = l31 & 7;                  // read-side slot XOR key

  f32x16 acc[FI][FJ];
#pragma unroll
  for (int i = 0; i < FI; i++)
#pragma unroll
    for (int j = 0; j < FJ; j++)
#pragma unroll
      for (int r = 0; r < 16; r++) acc[i][j][r] = 0.f;

  const int srow = tid >> 3;                // 32 rows per pass, 8 threads/row
  const int sslot = tid & 7;

  auto stage = [&](int buf, int k0) {
#pragma unroll
    for (int p = 0; p < 4; p++) {           // B: 128 rows
      int row = (p << 5) + srow;
      int sl  = (sslot ^ (row & 7)) << 3;
      gload16(Bt + (size_t)(n0 + row) * K + k0 + sl,
              &lB[buf][(row << 6) + (sslot << 3)]);
    }
#pragma unroll
    for (int p = 0; p < TM / 32; p++) {     // A: TM rows
      int row = (p << 5) + srow;
      int sl  = (sslot ^ (row & 7)) << 3;
      gload16(A + (size_t)(m0 + row) * K + k0 + sl,
              &lA[buf][(row << 6) + (sslot << 3)]);
    }
  };

  stage(0, 0);

  const int nkt = K >> 6;
  for (int kt = 0; kt < nkt; ++kt) {
    const int cur = kt & 1;
    __syncthreads();                        // drains stage(cur); protects buf[cur^1]
    if (kt + 1 < nkt) stage(cur ^ 1, (kt + 1) << 6);
    short8 af[FI][4], bf[FJ][4];
#pragma unroll
    for (int i = 0; i < FI; i++)
#pragma unroll
      for (int ks = 0; ks < 4; ks++)
        af[i][ks] = *(const short8*)&lA[cur][((wmo + (i << 5) + l31) << 6) +
                                            ((((ks << 1) + lh) ^ rsw) << 3)];
#pragma unroll
    for (int j = 0; j < FJ; j++)
#pragma unroll
      for (int ks = 0; ks < 4; ks++)
        bf[j][ks] = *(const short8*)&lB[cur][((wno + (j << 5) + l31) << 6) +
                                            ((((ks << 1) + lh) ^ rsw) << 3)];
#pragma unroll
    for (int i = 0; i < FI; i++)
#pragma unroll
      for (int j = 0; j < FJ; j++)
#pragma unroll
        for (int ks = 0; ks < 4; ks++)
          acc[i][j] = __builtin_amdgcn_mfma_f32_32x32x16_bf16(af[i][ks], bf[j][ks],
                                                              acc[i][j], 0, 0, 0);
  }

  // epilogue: col = lane&31 (fixed per fj), row = (reg&3)+8*(reg>>2)+4*lh
#pragma unroll
  for (int i = 0; i < FI; i++) {
#pragma unroll
    for (int j = 0; j < FJ; j++) {
      int col = n0 + wno + (j << 5) + l31;
      float bv = bias[col];
#pragma unroll
      for (int reg = 0; reg < 16; ++reg) {
        int m = m0 + wmo + (i << 5) + (reg & 3) + ((reg >> 2) << 3) + (lh << 2);
        float cvl = acc[i][j][reg] + bv;
        if (MODE == 0) {
          int bI = m >> 11, nI = m & 2047;
          if (col < 384) {
            int hh = col >> 6, dd = col & 63;
            oq[(((size_t)bI * kH + hh) * kN + nI) * 64 + dd] = f2b(cvl * kQPre);
          } else if (col < 768) {
            int c2 = col - 384; int hh = c2 >> 6, dd = c2 & 63;
            okk[(((size_t)bI * kH + hh) * kN + nI) * 64 + dd] = f2b(cvl);
          } else {
            int c2 = col - 768; int hh = c2 >> 6, dd = c2 & 63;
            ov[(((size_t)bI * kH + hh) * 64 + dd) * kN + nI] = f2b(cvl);
          }
        } else if (MODE == 1) {
          oh[(size_t)m * kDFF + col] = f2b(gelu_fast(cvl));
        } else {
          size_t idx = (size_t)m * kD + col;
          out[idx] = res[idx] + cvl;
        }
      }
    }
  }
}

// ---- flash attention, 32x32 frags, P^T in registers (R16/R17-verified) ------
// + T5 setprio around MFMA clusters (zero-correctness-risk scheduler hint).
__global__ __launch_bounds__(256) void k_attn(
    const unsigned short* __restrict__ Q, const unsigned short* __restrict__ Kg,
    const unsigned short* __restrict__ Vt, const float* __restrict__ x,
    float* __restrict__ x2) {
  __shared__ unsigned short sh[4 * 4096];     // lK[2] (0..8191) | lV[2] (8192..)
  unsigned short* lK = sh;
  unsigned short* lV = sh + 8192;
  const int tid = threadIdx.x, wid = tid >> 6, lane = tid & 63;
  const int swz = (blockIdx.x & 7) * (gridDim.x >> 3) + (blockIdx.x >> 3);
  const int bh = swz >> 5, qt = swz & 31;
  const int b = bh / kH, h = bh - b * kH;
  const unsigned short* Qp = Q  + (size_t)bh * kN * 64;
  const unsigned short* Kp = Kg + (size_t)bh * kN * 64;
  const unsigned short* Vp = Vt + (size_t)bh * 64 * kN;
  const int l31 = lane & 31, lh = lane >> 5;
  const int qh = wid & 1, kvh = wid >> 1;
  const int q0 = qt * 64;
  const int rsw7 = l31 & 7;                   // row-derived slot XOR key

  const int sr  = ((wid << 3) + (lane >> 3)); // staging rows 0..31 (+32 for p=1)
  const int scc = (lane & 7) << 3;            // linear LDS slot

  // Q B-frags: col q = q0+qh*32+l31, k(d) = ks*16+lh*8
  short8 qb[4];
#pragma unroll
  for (int ks = 0; ks < 4; ++ks)
    qb[ks] = *(const short8*)(Qp + (size_t)(q0 + qh * 32 + l31) * 64 + ks * 16 + lh * 8);

  f32x16 o[2];
#pragma unroll
  for (int dt = 0; dt < 2; ++dt)
#pragma unroll
    for (int r = 0; r < 16; r++) o[dt][r] = 0.f;
  float l_r = 0.f;

  auto stage = [&](int buf, int t) {
#pragma unroll
    for (int p = 0; p < 2; p++) {
      int r = sr + (p << 5);
      int sl = ((lane & 7) ^ (r & 7)) << 3;
      gload16(Kp + (size_t)(t * 64 + r) * 64 + sl, &lK[buf * 4096 + (r << 6) + scc]);
      gload16(Vp + (size_t)r * kN + t * 64 + sl,   &lV[buf * 4096 + (r << 6) + scc]);
    }
  };

  stage(0, 0);

  constexpr int kNT = kN / 64;                // 32 tiles, full KV
  for (int t = 0; t < kNT; ++t) {
    const int cur = t & 1;
    __syncthreads();                          // drains stage(cur); protects buf[cur^1]
    if (t + 1 < kNT) stage(cur ^ 1, t + 1);

    // S^T[kv32 of kvh][q32 of qh] = mfma(K_A, Q_B) over d=64 (4 k-steps)
    f32x16 s;
#pragma unroll
    for (int r = 0; r < 16; r++) s[r] = 0.f;
    __builtin_amdgcn_s_setprio(1);
#pragma unroll
    for (int ks = 0; ks < 4; ++ks) {
      short8 kf = *(const short8*)&lK[cur * 4096 + ((kvh * 32 + l31) << 6) +
                                      ((((ks << 1) + lh) ^ rsw7) << 3)];
      s = __builtin_amdgcn_mfma_f32_32x32x16_bf16(kf, qb[ks], s, 0, 0, 0);
    }
    __builtin_amdgcn_s_setprio(0);

    // P = exp2(s); pack groups g: Aw[g]=pk(p[4g],p[4g+1]), Bw[g]=pk(p[4g+2],p[4g+3])
    uint32_t Aw[4], Bw[4];
    float lsum = 0.f;
#pragma unroll
    for (int g = 0; g < 4; ++g) {
      float p0 = exp2fast(s[4 * g + 0]);
      float p1 = exp2fast(s[4 * g + 1]);
      float p2 = exp2fast(s[4 * g + 2]);
      float p3 = exp2fast(s[4 * g + 3]);
      lsum += (p0 + p1) + (p2 + p3);
      asm("v_cvt_pk_bf16_f32 %0, %1, %2" : "=v"(Aw[g]) : "v"(p0), "v"(p1));
      asm("v_cvt_pk_bf16_f32 %0, %1, %2" : "=v"(Bw[g]) : "v"(p2), "v"(p3));
    }
    l_r += lsum + __shfl_xor(lsum, 32, 64);   // wave's kv-half row-sum for q=l31

    // Build P^T B-frags in-register (reg group = lh_dest+2ks, src half = jj>>2)
    short8 pb[2];
#pragma unroll
    for (int ks = 0; ks < 2; ++ks) {
      uint32_t cA = lh ? Aw[2 * ks + 1] : Aw[2 * ks];
      uint32_t cB = lh ? Bw[2 * ks + 1] : Bw[2 * ks];
      uint32_t dA = lh ? Aw[2 * ks] : Aw[2 * ks + 1];
      uint32_t dB = lh ? Bw[2 * ks] : Bw[2 * ks + 1];
      uint32_t sA = __shfl_xor(dA, 32, 64);
      uint32_t sB = __shfl_xor(dB, 32, 64);
      union { uint32_t u[4]; short8 s8; } bld;
      bld.u[0] = lh ? sA : cA;
      bld.u[1] = lh ? sB : cB;
      bld.u[2] = lh ? cA : sA;
      bld.u[3] = lh ? cB : sB;
      pb[ks] = bld.s8;
    }

    // O^T[d 2x32][q32] += V^T P^T ; V^T A-frag: row d = dt*32+l31, k = kv local
    __builtin_amdgcn_s_setprio(1);
#pragma unroll
    for (int dt = 0; dt < 2; ++dt) {
#pragma unroll
      for (int ks = 0; ks < 2; ++ks) {
        short8 va = *(const short8*)&lV[cur * 4096 + (((dt << 5) + l31) << 6) +
                        ((((kvh << 2) + (ks << 1) + lh) ^ rsw7) << 3)];
        o[dt] = __builtin_amdgcn_mfma_f32_32x32x16_bf16(va, pb[ks], o[dt], 0, 0, 0);
      }
    }
    __builtin_amdgcn_s_setprio(0);
  }

  // ---- merge kv-halves + coalesced write: fb[q64][d64] f32 (stride 65) ----
  __syncthreads();                            // staging buffers dead from here
  float* fb = (float*)sh;                     // 64*65 f32 = 16.6KB
  float* lb = (float*)sh + 64 * 65;           // l totals [64]
  const int q = qh * 32 + l31;
  if (kvh == 1) {
#pragma unroll
    for (int dt = 0; dt < 2; ++dt)
#pragma unroll
      for (int reg = 0; reg < 16; ++reg) {
        int d = (dt << 5) + (reg & 3) + ((reg >> 2) << 3) + (lh << 2);
        fb[q * 65 + d] = o[dt][reg];
      }
    if (lh == 0) lb[q] = l_r;
  }
  __syncthreads();
  if (kvh == 0) {
#pragma unroll
    for (int dt = 0; dt < 2; ++dt)
#pragma unroll
      for (int reg = 0; reg < 16; ++reg) {
        int d = (dt << 5) + (reg & 3) + ((reg >> 2) << 3) + (lh << 2);
        fb[q * 65 + d] += o[dt][reg];
      }
    if (lh == 0) lb[q] += l_r;
  }
  __syncthreads();
  // write-out: thread -> (row=tid>>2, 16-d chunk), fully coalesced x/x2
  {
    int row = tid >> 2, dc = (tid & 3) << 4;
    float inv = __builtin_amdgcn_rcpf(lb[row]);
    size_t base = ((size_t)(b * kN + q0 + row)) * kD + h * 64 + dc;
#pragma unroll
    for (int i = 0; i < 16; i += 4) {
      float4 xv = *(const float4*)(x + base + i);
      float4 ov;
      ov.x = xv.x + fb[row * 65 + dc + i + 0] * inv;
      ov.y = xv.y + fb[row * 65 + dc + i + 1] * inv;
      ov.z = xv.z + fb[row * 65 + dc + i + 2] * inv;
      ov.w = xv.w + fb[row * 65 + dc + i + 3] * inv;
      *(float4*)(x2 + base + i) = ov;
    }
  }
}

extern "C" void kernel_launch(void* const* d_in, const int* in_sizes, int n_in,
                              void* d_out, int out_size, void* d_ws, size_t ws_size,
                              hipStream_t stream) {
  const float* x    = (const float*)d_in[0];
  const float* ng   = (const float*)d_in[1];
  const float* nb   = (const float*)d_in[2];
  const float* wqkv = (const float*)d_in[3];
  const float* bqkv = (const float*)d_in[4];
  const float* w1   = (const float*)d_in[5];
  const float* b1   = (const float*)d_in[6];
  const float* w2   = (const float*)d_in[7];
  const float* b2   = (const float*)d_in[8];
  float* out = (float*)d_out;

  char* p = (char*)d_ws;
  auto take = [&](size_t bytes) -> char* {
    char* r = p; p += (bytes + 255) & ~(size_t)255; return r;
  };
  unsigned short* y     = (unsigned short*)take((size_t)kM * kD * 2);
  unsigned short* wqkvT = (unsigned short*)take((size_t)3 * kD * kD * 2);
  unsigned short* w1T   = (unsigned short*)take((size_t)kDFF * kD * 2);
  unsigned short* w2T   = (unsigned short*)take((size_t)kD * kDFF * 2);
  unsigned short* Qw    = (unsigned short*)take((size_t)kM * kD * 2);
  unsigned short* Kw    = (unsigned short*)take((size_t)kM * kD * 2);
  unsigned short* Vtw   = (unsigned short*)take((size_t)kM * kD * 2);
  float*          x2    = (float*)take((size_t)kM * kD * 4);
  unsigned short* hbuf  = (unsigned short*)take((size_t)kM * kDFF * 2);

  k_pre<<<492 + kM / 4, 256, 0, stream>>>(wqkv, wqkvT, w1, w1T, w2, w2T,
                                          x, ng, nb, y);
  k_gemm<0, 64><<<128 * 9, 256, 0, stream>>>(y, wqkvT, bqkv, kD, 3 * kD, 128,
                                             Qw, Kw, Vtw, nullptr, nullptr, nullptr);
  k_attn<<<kBH * 32, 256, 0, stream>>>(Qw, Kw, Vtw, x, x2);
  k_layernorm<<<kM / 4, 256, 0, stream>>>(x2, ng, nb, y);
  k_gemm<1, 64><<<128 * 16, 256, 0, stream>>>(y, w1T, b1, kD, kDFF, 128,
                                              nullptr, nullptr, nullptr, hbuf, nullptr, nullptr);
  k_gemm<2, 32><<<256 * 3, 256, 0, stream>>>(hbuf, w2T, b2, kDFF, kD, 256,
                                             nullptr, nullptr, nullptr, nullptr, x2, out);
}